// Round 2
// baseline (214.647 us; speedup 1.0000x reference)
//
#include <hip/hip_runtime.h>
#include <hip/hip_bf16.h>
#include <cstddef>

// 3-layer tanh RNN (B=8192, T=80, D=32, H=64), fused, MFMA.
// SYSTOLIC LAYER PIPELINE, 4-STEP CHUNKS, register-carried recurrence (K=32),
// R13: DUAL BATCH-TILE per wave (32 rows/block, 256 blocks).
//
// Block = 192 thr = 3 waves; wave wv = layer wv. Interval m (0..21): wave wv
// computes its layer for t = 4*(m-wv) .. 4*(m-wv)+3 for TWO independent
// 16-row batch tiles (u=0,1) sharing the same VGPR-resident weights.
// Rationale (R12 post-mortem): at 512 blocks, 6 waves/CU on 4 SIMDs -> two
// waves share a SIMD, barrier waits on the shared-SIMD straggler, and ~55%
// of cycles idle on latency. 256 blocks x 3 waves = 1 wave/SIMD (no issue
// sharing) and the dual tile gives each wave two independent MFMA/tanh
// streams to self-hide the serial recurrence chain. Same 22 intervals.
//
//   - ONE barrier per 4-step interval;
//   - own recurrence register-carried at K=32 via k-permuted Whh frags:
//     (hf[2h]||hf[2h+1]) is a K=32 B-operand, slot i = h[32h+16(i>>2)+4q+(i&3)]
//     (bijection absorbed into the Whh A-frag gather at load time);
//   - LDS ring hb[layer<2][t&7][batch 32][j]: slot sets disjoint mod 8;
//   - wave-0 x prefetched one interval ahead as PACKED bf16 (convert at
//     refill) to curb VGPR; drains across the 4 compute steps.
//
// MFMA maps (verified R2-R11):
//   K=32 A: A[m=lane&15][k=8q+i]; B: B[k=8q+i][n=lane&15]  (q=lane>>4)
//   16x16 D: D[row=4q+r][col=lane&15]
// tanh via exp2 (bias pre-scaled by 2*log2e) - numerics identical to R2-R12.

typedef __attribute__((ext_vector_type(8))) short s16x8;
typedef __attribute__((ext_vector_type(4))) short s16x4;
typedef __attribute__((ext_vector_type(4))) float fx4;

#define MFMA32(A, B, C) __builtin_amdgcn_mfma_f32_16x16x32_bf16((A), (B), (C), 0, 0, 0)

#if __has_builtin(__builtin_amdgcn_exp2f)
#define EXP2F(x) __builtin_amdgcn_exp2f(x)
#else
#define EXP2F(x) exp2f(x)
#endif
#if __has_builtin(__builtin_amdgcn_rcpf)
#define RCPF(x) __builtin_amdgcn_rcpf(x)
#else
#define RCPF(x) (1.0f / (x))
#endif

static constexpr float K2LOG2E = 2.8853900817779268f;  // 2*log2(e)

__device__ __forceinline__ short f2bf(float f) {  // RNE float->bf16 (weights, one-time)
  union { float f; unsigned u; } v; v.f = f;
  unsigned r = v.u + 0x7FFFu + ((v.u >> 16) & 1u);
  return (short)(r >> 16);
}
__device__ __forceinline__ float bf2f(short s) {
  union { unsigned u; float f; } v; v.u = ((unsigned)(unsigned short)s) << 16;
  return v.f;
}
__device__ __forceinline__ unsigned pk2bf(float a, float b) {  // v_cvt_pk_bf16_f32
  float2 t; t.x = a; t.y = b;
  union { __hip_bfloat162 h; unsigned u; } c;
  c.h = __float22bfloat162_rn(t);
  return c.u;
}

__device__ __forceinline__ s16x8 wfragA32(const float* W, int ncols, int row, int col0) {
  const float* p = W + row * ncols + col0;
  s16x8 r;
#pragma unroll
  for (int i = 0; i < 8; ++i) r[i] = f2bf(p[i]);
  return r;
}

// k-permuted Whh A-frag for the K=32 register-carried recurrence (half h=0,1):
// slot i  <-  Whh[row][ 32h + 16*(i>>2) + 4q + (i&3) ]
__device__ __forceinline__ s16x8 wfragWhh32(const float* W, int row, int q, int h) {
  const float* p = W + row * 64 + 32 * h + 4 * q;
  s16x8 r;
#pragma unroll
  for (int i = 0; i < 4; ++i) r[i] = f2bf(p[i]);
#pragma unroll
  for (int i = 0; i < 4; ++i) r[4 + i] = f2bf(p[16 + i]);
  return r;
}

// load 8 contiguous floats of x and pack to a K=32 B-frag piece (8 bf16)
__device__ __forceinline__ s16x8 load_pack_x(const float* p) {
  fx4 a = *(const fx4*)(p);
  fx4 b = *(const fx4*)(p + 4);
  union { unsigned u[4]; s16x8 v; } xp;
  xp.u[0] = pk2bf(a[0], a[1]);
  xp.u[1] = pk2bf(a[2], a[3]);
  xp.u[2] = pk2bf(b[0], b[1]);
  xp.u[3] = pk2bf(b[2], b[3]);
  return xp.v;
}

// tanh(acc + bias) (bias pre-scaled by 2*log2e) -> packed bf16.
__device__ __forceinline__ s16x4 tanh_pack(fx4 acc, const float* bs) {
  float h[4];
#pragma unroll
  for (int r = 0; r < 4; ++r) {
    float e = EXP2F(__builtin_fmaf(acc[r], K2LOG2E, bs[r]));
    h[r] = __builtin_fmaf(-2.f, RCPF(e + 1.f), 1.f);
  }
  union { unsigned u[2]; s16x4 v; } p;
  p.u[0] = pk2bf(h[0], h[1]);
  p.u[1] = pk2bf(h[2], h[3]);
  return p.v;
}

union U8 { s16x8 v; s16x4 h[2]; };

__global__ __launch_bounds__(192, 1) void rnn3_dual(
    const float* __restrict__ x,
    const float* __restrict__ Wih0, const float* __restrict__ Whh0,
    const float* __restrict__ bih0, const float* __restrict__ bhh0,
    const float* __restrict__ Wih1, const float* __restrict__ Whh1,
    const float* __restrict__ bih1, const float* __restrict__ bhh1,
    const float* __restrict__ Wih2, const float* __restrict__ Whh2,
    const float* __restrict__ bih2, const float* __restrict__ bhh2,
    const float* __restrict__ Wfc, const float* __restrict__ bfc,
    float* __restrict__ out)
{
  __shared__ __align__(16) short hb[2][8][32][72];  // [layer<2][t&7][batch][j], 73728 B

  const int tid = threadIdx.x;
  const int wv  = __builtin_amdgcn_readfirstlane(tid >> 6);  // 0..2 == layer
  const int ln  = tid & 63;
  const int q   = ln >> 4;        // K=32 k-quad / D row-quad
  const int m15 = ln & 15;
  const int bbase = (int)blockIdx.x * 32;

  // ---------- this wave's layer parameters ----------
  const float* Wih = (wv == 0) ? Wih0 : (wv == 1) ? Wih1 : Wih2;
  const float* Whh = (wv == 0) ? Whh0 : (wv == 1) ? Whh1 : Whh2;
  const float* bi  = (wv == 0) ? bih0 : (wv == 1) ? bih1 : bih2;
  const float* bh  = (wv == 0) ? bhh0 : (wv == 1) ? bhh1 : bhh2;
  const int kin = (wv == 0) ? 32 : 64;

  // ---------- weights (VGPR-resident, shared by both batch tiles) ----------
  s16x8 wiA[4], wiB[4];
  s16x8 wh32[4][2];
  const s16x8 z8 = {0, 0, 0, 0, 0, 0, 0, 0};
#pragma unroll
  for (int t4 = 0; t4 < 4; ++t4) {
    const int row = 16 * t4 + m15;
    wiA[t4] = wfragA32(Wih, kin, row, 8 * q);
    wiB[t4] = wv ? wfragA32(Wih, 64, row, 32 + 8 * q) : z8;   // layer 0: K=32 only
    wh32[t4][0] = wfragWhh32(Whh, row, q, 0);
    wh32[t4][1] = wfragWhh32(Whh, row, q, 1);
  }

  // ---------- biases pre-scaled; lane's j = 16*t4 + 4*q + r ----------
  float bsc[4][4];
#pragma unroll
  for (int t4 = 0; t4 < 4; ++t4)
#pragma unroll
    for (int r = 0; r < 4; ++r) {
      const int j = 16 * t4 + 4 * q + r;
      bsc[t4][r] = (bi[j] + bh[j]) * K2LOG2E;
    }

  const fx4 z4 = {0.f, 0.f, 0.f, 0.f};
  U8 hA[2], hB[2];                 // own state h_wv(t-1) per tile, j 0..31 / 32..63
  hA[0].v = z8; hB[0].v = z8; hA[1].v = z8; hB[1].v = z8;

  // ---------- wave-0: packed x prefetch (one interval ahead) ----------
  const float* xr0 = x + (size_t)(bbase + m15) * (80 * 32) + 8 * q;
  const float* xr1 = x + (size_t)(bbase + 16 + m15) * (80 * 32) + 8 * q;
  s16x8 xin[2][4];
  if (wv == 0) {
#pragma unroll
    for (int jj = 0; jj < 4; ++jj) {          // preload t = 0..3, both tiles
      xin[0][jj] = load_pack_x(xr0 + jj * 32);
      xin[1][jj] = load_pack_x(xr1 + jj * 32);
    }
  }

  for (int m = 0; m < 22; ++m) {
    const int lt0 = 4 * (m - wv);             // first t of this interval
    if (0 <= lt0 && lt0 <= 76) {              // wave-uniform
      // ---- interval top: gather all 4 inputs for both tiles ----
      s16x8 inA[2][4], inB[2][4];
      if (wv == 0) {
#pragma unroll
        for (int u = 0; u < 2; ++u)
#pragma unroll
          for (int jj = 0; jj < 4; ++jj) {
            inA[u][jj] = xin[u][jj];
            inB[u][jj] = z8;
          }
        // refill for next interval (t = lt0+4 .. lt0+7, clamped); packs land
        // whenever loads return, hidden under the 4 compute steps
#pragma unroll
        for (int jj = 0; jj < 4; ++jj) {
          const int tt = (lt0 + 4 + jj <= 79) ? lt0 + 4 + jj : 79;
          xin[0][jj] = load_pack_x(xr0 + tt * 32);
          xin[1][jj] = load_pack_x(xr1 + tt * 32);
        }
      } else {
#pragma unroll
        for (int u = 0; u < 2; ++u)
#pragma unroll
          for (int jj = 0; jj < 4; ++jj) {
            const short* up = &hb[wv - 1][(lt0 + jj) & 7][16 * u + m15][8 * q];
            inA[u][jj] = *(const s16x8*)(up);
            inB[u][jj] = *(const s16x8*)(up + 32);
          }
      }
      // ---- 4 sequential steps; two independent tiles interleaved ----
#pragma unroll
      for (int jj = 0; jj < 4; ++jj) {
        const int st = (lt0 + jj) & 7;
        fx4 acc[2][4];
#pragma unroll
        for (int t4 = 0; t4 < 4; ++t4)
#pragma unroll
          for (int u = 0; u < 2; ++u)
            acc[u][t4] = MFMA32(wiA[t4], inA[u][jj], z4);
        if (wv) {
#pragma unroll
          for (int t4 = 0; t4 < 4; ++t4)
#pragma unroll
            for (int u = 0; u < 2; ++u)
              acc[u][t4] = MFMA32(wiB[t4], inB[u][jj], acc[u][t4]);
        }
#pragma unroll
        for (int t4 = 0; t4 < 4; ++t4)
#pragma unroll
          for (int u = 0; u < 2; ++u)
            acc[u][t4] = MFMA32(wh32[t4][0], hA[u].v, acc[u][t4]);
#pragma unroll
        for (int t4 = 0; t4 < 4; ++t4)
#pragma unroll
          for (int u = 0; u < 2; ++u)
            acc[u][t4] = MFMA32(wh32[t4][1], hB[u].v, acc[u][t4]);
        // tanh -> new own state + LDS publish for downstream (layers 0,1 only)
#pragma unroll
        for (int u = 0; u < 2; ++u) {
          U8 nA, nB;
#pragma unroll
          for (int t4 = 0; t4 < 4; ++t4) {
            s16x4 hv = tanh_pack(acc[u][t4], bsc[t4]);
            if (t4 < 2) nA.h[t4] = hv; else nB.h[t4 - 2] = hv;
            if (wv < 2) {
              *(s16x4*)(&hb[wv][st][16 * u + m15][4 * q + 16 * t4]) = hv;
            }
          }
          hA[u] = nA; hB[u] = nB;
        }
      }
    }
    __syncthreads();                          // ONE barrier per 4-step interval
  }

  // ---------- FC head: wave 2's state == h2(79) per tile ----------
  if (wv == 2) {
    float svs[2];
#pragma unroll
    for (int u = 0; u < 2; ++u) {
      float sv = 0.f;
#pragma unroll
      for (int kf = 0; kf < 4; ++kf) {
        const s16x4 hh = (kf < 2) ? hA[u].h[kf] : hB[u].h[kf - 2];
#pragma unroll
        for (int i = 0; i < 4; ++i)
          sv += bf2f(hh[i]) * Wfc[16 * kf + 4 * q + i];
      }
      sv += __shfl_xor(sv, 16, 64);
      sv += __shfl_xor(sv, 32, 64);
      svs[u] = sv;
    }
    if (ln < 16) {
      out[bbase + ln]      = svs[0] + bfc[0];
      out[bbase + 16 + ln] = svs[1] + bfc[0];
    }
  }
}

extern "C" void kernel_launch(void* const* d_in, const int* in_sizes, int n_in,
                              void* d_out, int out_size, void* d_ws, size_t ws_size,
                              hipStream_t stream) {
  const float* x    = (const float*)d_in[0];
  const float* Wih0 = (const float*)d_in[1];
  const float* Whh0 = (const float*)d_in[2];
  const float* bih0 = (const float*)d_in[3];
  const float* bhh0 = (const float*)d_in[4];
  const float* Wih1 = (const float*)d_in[5];
  const float* Whh1 = (const float*)d_in[6];
  const float* bih1 = (const float*)d_in[7];
  const float* bhh1 = (const float*)d_in[8];
  const float* Wih2 = (const float*)d_in[9];
  const float* Whh2 = (const float*)d_in[10];
  const float* bih2 = (const float*)d_in[11];
  const float* bhh2 = (const float*)d_in[12];
  const float* Wfc  = (const float*)d_in[13];
  const float* bfc  = (const float*)d_in[14];

  // 256 blocks x 192 thr (3 waves = 3 pipelined layers), 32 batch rows/block:
  // 3 waves/CU -> one wave per SIMD, dual independent tiles per wave for ILP.
  rnn3_dual<<<dim3(256), dim3(192), 0, stream>>>(
      x, Wih0, Whh0, bih0, bhh0, Wih1, Whh1, bih1, bhh1,
      Wih2, Whh2, bih2, bhh2, Wfc, bfc, (float*)d_out);
}

// Round 3
// 208.367 us; speedup vs baseline: 1.0301x; 1.0301x over previous
//
#include <hip/hip_runtime.h>
#include <hip/hip_bf16.h>
#include <cstddef>

// 3-layer tanh RNN (B=8192, T=80, D=32, H=64), fused, MFMA.
// SYSTOLIC LAYER PIPELINE, 4-STEP CHUNKS, register-carried recurrence (K=32).
// R14: LUT-TANH - transcendental-free steady loop.
//
// R13 post-mortem: 256 blocks = 0.75 waves/SIMD (1 SIMD/CU dead) -> regression;
// grid reverted to R12's 512 blocks x 192 thr (2 blocks/CU, 1.5 waves/SIMD).
// R12/R13 counter reconciliation: VALUBusy counts issue slots; v_exp_f32/
// v_rcp_f32 occupy the VALU pipe >=16 cyc each (wave64). 32 trans/step/wave
// saturate the trans pipe (82-164k cyc/SIMD vs 181k wall) -> tanh via exp2+rcp
// is the wall, and extra ILP (R13) can't help a saturated pipe.
// Fix: tanh by 512-interval LDS LUT + linear interp on z in [-4,4]:
//   p = fma(acc, 64, bias*64+256); clamp; i=floor; ds_read_b64 (y,dy); lerp.
//   ~14 VALU-cyc + 1 LDS op per value (LDS pipe overlaps VALU), ZERO trans.
//   |err| <= 2.3e-5 (lerp) / 6.7e-4 (clamp |z|>4) - ~100x below bf16 quantum.
// LUT built once at kernel start from the exact exp2-based tanh (+1 barrier).
//
// Structure (R12, measured 75.4us):
//   - wave wv = layer wv; interval m: t = 4*(m-wv)..+3; ONE barrier/interval;
//   - recurrence register-carried at K=32 via k-permuted Whh frags
//     (slot i = h[32h+16(i>>2)+4q+(i&3)], bijection folded into weight gather);
//   - LDS ring hb[layer<2][t&7][16][72], slot sets disjoint mod 8;
//   - wave-0 x prefetched one interval ahead.
// MFMA maps (verified R2-R11):
//   K=32 A: A[m=lane&15][k=8q+i]; B: B[k=8q+i][n=lane&15]  (q=lane>>4)
//   16x16 D: D[row=4q+r][col=lane&15]

typedef __attribute__((ext_vector_type(8))) short s16x8;
typedef __attribute__((ext_vector_type(4))) short s16x4;
typedef __attribute__((ext_vector_type(4))) float fx4;

#define MFMA32(A, B, C) __builtin_amdgcn_mfma_f32_16x16x32_bf16((A), (B), (C), 0, 0, 0)

#if __has_builtin(__builtin_amdgcn_exp2f)
#define EXP2F(x) __builtin_amdgcn_exp2f(x)
#else
#define EXP2F(x) exp2f(x)
#endif
#if __has_builtin(__builtin_amdgcn_rcpf)
#define RCPF(x) __builtin_amdgcn_rcpf(x)
#else
#define RCPF(x) (1.0f / (x))
#endif

static constexpr float K2LOG2E = 2.8853900817779268f;  // 2*log2(e)

__device__ __forceinline__ short f2bf(float f) {  // RNE float->bf16 (weights, one-time)
  union { float f; unsigned u; } v; v.f = f;
  unsigned r = v.u + 0x7FFFu + ((v.u >> 16) & 1u);
  return (short)(r >> 16);
}
__device__ __forceinline__ float bf2f(short s) {
  union { unsigned u; float f; } v; v.u = ((unsigned)(unsigned short)s) << 16;
  return v.f;
}
__device__ __forceinline__ unsigned pk2bf(float a, float b) {  // v_cvt_pk_bf16_f32
  float2 t; t.x = a; t.y = b;
  union { __hip_bfloat162 h; unsigned u; } c;
  c.h = __float22bfloat162_rn(t);
  return c.u;
}

__device__ __forceinline__ s16x8 wfragA32(const float* W, int ncols, int row, int col0) {
  const float* p = W + row * ncols + col0;
  s16x8 r;
#pragma unroll
  for (int i = 0; i < 8; ++i) r[i] = f2bf(p[i]);
  return r;
}

// k-permuted Whh A-frag for the K=32 register-carried recurrence (half h=0,1):
// slot i  <-  Whh[row][ 32h + 16*(i>>2) + 4q + (i&3) ]
__device__ __forceinline__ s16x8 wfragWhh32(const float* W, int row, int q, int h) {
  const float* p = W + row * 64 + 32 * h + 4 * q;
  s16x8 r;
#pragma unroll
  for (int i = 0; i < 4; ++i) r[i] = f2bf(p[i]);
#pragma unroll
  for (int i = 0; i < 4; ++i) r[4 + i] = f2bf(p[16 + i]);
  return r;
}

// load 8 contiguous floats of x and pack to a K=32 B-frag piece (8 bf16)
__device__ __forceinline__ s16x8 load_pack_x(const float* p) {
  fx4 a = *(const fx4*)(p);
  fx4 b = *(const fx4*)(p + 4);
  union { unsigned u[4]; s16x8 v; } xp;
  xp.u[0] = pk2bf(a[0], a[1]);
  xp.u[1] = pk2bf(a[2], a[3]);
  xp.u[2] = pk2bf(b[0], b[1]);
  xp.u[3] = pk2bf(b[2], b[3]);
  return xp.v;
}

// tanh(acc + bias) via LDS LUT + lerp -> packed bf16. pb = bias*64 + 256.
__device__ __forceinline__ s16x4 lut_pack(fx4 acc, const float* pb, const float2* lut) {
  float h[4];
#pragma unroll
  for (int r = 0; r < 4; ++r) {
    float p = __builtin_fmaf(acc[r], 64.f, pb[r]);
    p = fminf(fmaxf(p, 0.f), 511.99f);        // -> v_med3_f32
    int i = (int)p;
    float fr = p - (float)i;
    float2 e = lut[i];                         // ds_read_b64: (y_i, y_{i+1}-y_i)
    h[r] = __builtin_fmaf(fr, e.y, e.x);
  }
  union { unsigned u[2]; s16x4 v; } pk;
  pk.u[0] = pk2bf(h[0], h[1]);
  pk.u[1] = pk2bf(h[2], h[3]);
  return pk.v;
}

union U8 { s16x8 v; s16x4 h[2]; };

__global__ __launch_bounds__(192, 2) void rnn3_lut(
    const float* __restrict__ x,
    const float* __restrict__ Wih0, const float* __restrict__ Whh0,
    const float* __restrict__ bih0, const float* __restrict__ bhh0,
    const float* __restrict__ Wih1, const float* __restrict__ Whh1,
    const float* __restrict__ bih1, const float* __restrict__ bhh1,
    const float* __restrict__ Wih2, const float* __restrict__ Whh2,
    const float* __restrict__ bih2, const float* __restrict__ bhh2,
    const float* __restrict__ Wfc, const float* __restrict__ bfc,
    float* __restrict__ out)
{
  __shared__ __align__(16) short hb[2][8][16][72];  // 36864 B
  __shared__ __align__(8) float2 lut[513];          // 4104 B: (tanh(z_i), delta)

  const int tid = threadIdx.x;
  const int wv  = __builtin_amdgcn_readfirstlane(tid >> 6);  // 0..2 == layer
  const int ln  = tid & 63;
  const int q   = ln >> 4;        // K=32 k-quad / D row-quad
  const int m15 = ln & 15;
  const int bbase = (int)blockIdx.x * 16;

  // ---------- build tanh LUT (one-time; z_i = i/64 - 4, i = 0..512) ----------
  for (int i = tid; i < 513; i += 192) {
    float z0 = (float)i * 0.015625f - 4.f;
    float z1 = z0 + 0.015625f;
    float e0 = EXP2F(z0 * K2LOG2E);
    float e1 = EXP2F(z1 * K2LOG2E);
    float y0 = __builtin_fmaf(-2.f, RCPF(e0 + 1.f), 1.f);
    float y1 = __builtin_fmaf(-2.f, RCPF(e1 + 1.f), 1.f);
    float2 ent; ent.x = y0; ent.y = y1 - y0;
    lut[i] = ent;
  }

  // ---------- this wave's layer parameters ----------
  const float* Wih = (wv == 0) ? Wih0 : (wv == 1) ? Wih1 : Wih2;
  const float* Whh = (wv == 0) ? Whh0 : (wv == 1) ? Whh1 : Whh2;
  const float* bi  = (wv == 0) ? bih0 : (wv == 1) ? bih1 : bih2;
  const float* bh  = (wv == 0) ? bhh0 : (wv == 1) ? bhh1 : bhh2;
  const int kin = (wv == 0) ? 32 : 64;

  // ---------- weights (VGPR-resident) ----------
  s16x8 wiA[4], wiB[4];
  s16x8 wh32[4][2];
  const s16x8 z8 = {0, 0, 0, 0, 0, 0, 0, 0};
#pragma unroll
  for (int t4 = 0; t4 < 4; ++t4) {
    const int row = 16 * t4 + m15;
    wiA[t4] = wfragA32(Wih, kin, row, 8 * q);
    wiB[t4] = wv ? wfragA32(Wih, 64, row, 32 + 8 * q) : z8;   // layer 0: K=32 only
    wh32[t4][0] = wfragWhh32(Whh, row, q, 0);
    wh32[t4][1] = wfragWhh32(Whh, row, q, 1);
  }

  // ---------- biases folded into LUT index map: pb = bias*64 + 256 ----------
  float pb[4][4];
#pragma unroll
  for (int t4 = 0; t4 < 4; ++t4)
#pragma unroll
    for (int r = 0; r < 4; ++r) {
      const int j = 16 * t4 + 4 * q + r;
      pb[t4][r] = __builtin_fmaf(bi[j] + bh[j], 64.f, 256.f);
    }

  const fx4 z4 = {0.f, 0.f, 0.f, 0.f};
  const s16x4 z2 = {0, 0, 0, 0};
  U8 hA, hB;                       // own state h_wv(t-1): hA=(j 0..31), hB=(j 32..63)
  hA.v = z8; hB.v = z8; (void)z2;

  // ---------- wave-0: packed x prefetch (one interval ahead) ----------
  const float* xr = x + (size_t)(bbase + m15) * (80 * 32) + 8 * q;
  s16x8 xin[4];
  if (wv == 0) {
#pragma unroll
    for (int jj = 0; jj < 4; ++jj) xin[jj] = load_pack_x(xr + jj * 32);
  }

  __syncthreads();                              // LUT ready before interval 0

  for (int m = 0; m < 22; ++m) {
    const int lt0 = 4 * (m - wv);             // first t of this interval
    if (0 <= lt0 && lt0 <= 76) {              // wave-uniform
      // ---- interval top: gather all 4 inputs ----
      s16x8 inA[4], inB[4];
      if (wv == 0) {
#pragma unroll
        for (int jj = 0; jj < 4; ++jj) { inA[jj] = xin[jj]; inB[jj] = z8; }
        // refill for next interval (t = lt0+4 .. lt0+7, clamped)
#pragma unroll
        for (int jj = 0; jj < 4; ++jj) {
          const int tt = (lt0 + 4 + jj <= 79) ? lt0 + 4 + jj : 79;
          xin[jj] = load_pack_x(xr + tt * 32);
        }
      } else {
#pragma unroll
        for (int jj = 0; jj < 4; ++jj) {
          const short* up = &hb[wv - 1][(lt0 + jj) & 7][m15][8 * q];
          inA[jj] = *(const s16x8*)(up);
          inB[jj] = *(const s16x8*)(up + 32);
        }
      }
      // ---- 4 sequential steps (own recurrence register-carried, K=32) ----
#pragma unroll
      for (int jj = 0; jj < 4; ++jj) {
        const int st = (lt0 + jj) & 7;
        fx4 acc[4];
#pragma unroll
        for (int t4 = 0; t4 < 4; ++t4) acc[t4] = MFMA32(wiA[t4], inA[jj], z4);
        if (wv) {
#pragma unroll
          for (int t4 = 0; t4 < 4; ++t4) acc[t4] = MFMA32(wiB[t4], inB[jj], acc[t4]);
        }
#pragma unroll
        for (int t4 = 0; t4 < 4; ++t4) acc[t4] = MFMA32(wh32[t4][0], hA.v, acc[t4]);
#pragma unroll
        for (int t4 = 0; t4 < 4; ++t4) acc[t4] = MFMA32(wh32[t4][1], hB.v, acc[t4]);
        // LUT tanh -> new own state + LDS publish for downstream (layers 0,1)
        U8 nA, nB;
#pragma unroll
        for (int t4 = 0; t4 < 4; ++t4) {
          s16x4 hv = lut_pack(acc[t4], pb[t4], lut);
          if (t4 < 2) nA.h[t4] = hv; else nB.h[t4 - 2] = hv;
          if (wv < 2) {
            *(s16x4*)(&hb[wv][st][m15][4 * q + 16 * t4]) = hv;
          }
        }
        hA = nA; hB = nB;
      }
    }
    __syncthreads();                          // ONE barrier per 4-step interval
  }

  // ---------- FC head: wave 2's state == h2(79), j = 16*kf + 4*q + i ----------
  if (wv == 2) {
    float sv = 0.f;
#pragma unroll
    for (int kf = 0; kf < 4; ++kf) {
      const s16x4 hh = (kf < 2) ? hA.h[kf] : hB.h[kf - 2];
#pragma unroll
      for (int i = 0; i < 4; ++i)
        sv += bf2f(hh[i]) * Wfc[16 * kf + 4 * q + i];
    }
    sv += __shfl_xor(sv, 16, 64);
    sv += __shfl_xor(sv, 32, 64);
    if (ln < 16) out[bbase + ln] = sv + bfc[0];
  }
}

extern "C" void kernel_launch(void* const* d_in, const int* in_sizes, int n_in,
                              void* d_out, int out_size, void* d_ws, size_t ws_size,
                              hipStream_t stream) {
  const float* x    = (const float*)d_in[0];
  const float* Wih0 = (const float*)d_in[1];
  const float* Whh0 = (const float*)d_in[2];
  const float* bih0 = (const float*)d_in[3];
  const float* bhh0 = (const float*)d_in[4];
  const float* Wih1 = (const float*)d_in[5];
  const float* Whh1 = (const float*)d_in[6];
  const float* bih1 = (const float*)d_in[7];
  const float* bhh1 = (const float*)d_in[8];
  const float* Wih2 = (const float*)d_in[9];
  const float* Whh2 = (const float*)d_in[10];
  const float* bih2 = (const float*)d_in[11];
  const float* bhh2 = (const float*)d_in[12];
  const float* Wfc  = (const float*)d_in[13];
  const float* bfc  = (const float*)d_in[14];

  // 512 blocks x 192 thr (3 waves = 3 pipelined layers), 16 batch rows/block:
  // 2 blocks/CU, 1.5 waves/SIMD (R12 config - best measured).
  rnn3_lut<<<dim3(512), dim3(192), 0, stream>>>(
      x, Wih0, Whh0, bih0, bhh0, Wih1, Whh1, bih1, bhh1,
      Wih2, Whh2, bih2, bhh2, Wfc, bfc, (float*)d_out);
}

// Round 4
// 186.428 us; speedup vs baseline: 1.1514x; 1.1177x over previous
//
#include <hip/hip_runtime.h>
#include <hip/hip_bf16.h>
#include <cstddef>

// 3-layer tanh RNN (B=8192, T=80, D=32, H=64), fused, MFMA.
// SYSTOLIC LAYER PIPELINE, 4-STEP CHUNKS, register-carried recurrence (K=32).
// R15: HOISTED INPUT-PROJECTION - all 16 input MFMAs fired at interval top.
//
// R14 post-mortem: LUT-tanh regressed (75.4 -> 96.9us; bank conflicts 2M->10M).
// VALUBusy only moved 39->36% despite deleting 32 trans/step => trans ops are
// near full-rate; the trans pipe was never the wall. The wall is EXPOSED
// LATENCY at 1.5 waves/SIMD (grid-capped 6 waves/CU): interval-top ds_read
// latency + 4x serial 4-deep MFMA accumulate chains (wiA->wiB->wh0->wh1).
// Fix: input-projection MFMAs (wiA/wiB) don't depend on the recurrence;
// compute accp[jj][t4] for ALL 4 steps at interval top as one independent
// 16-MFMA pool (overlaps the ds_read latency), leaving only the 2-deep
// recurrence accumulate + tanh on each step's serial chain. Accumulate order
// per acc unchanged -> bit-identical numerics vs R12.
//
// Structure (R12, measured 75.4us):
//   - wave wv = layer wv; interval m: t = 4*(m-wv)..+3; ONE barrier/interval;
//   - recurrence register-carried at K=32 via k-permuted Whh frags
//     (slot i = h[32h+16(i>>2)+4q+(i&3)], bijection folded into weight gather);
//   - LDS ring hb[layer<2][t&7][16][72], slot sets disjoint mod 8;
//   - wave-0 x double-buffered RAW in registers (fx4), packed at interval top,
//     refill issued right after packing (T14 issue-early/consume-late).
// MFMA maps (verified R2-R11):
//   K=32 A: A[m=lane&15][k=8q+i]; B: B[k=8q+i][n=lane&15]  (q=lane>>4)
//   16x16 D: D[row=4q+r][col=lane&15]
// tanh via exp2 (bias pre-scaled by 2*log2e) - numerics identical to R2-R12.

typedef __attribute__((ext_vector_type(8))) short s16x8;
typedef __attribute__((ext_vector_type(4))) short s16x4;
typedef __attribute__((ext_vector_type(4))) float fx4;

#define MFMA32(A, B, C) __builtin_amdgcn_mfma_f32_16x16x32_bf16((A), (B), (C), 0, 0, 0)

#if __has_builtin(__builtin_amdgcn_exp2f)
#define EXP2F(x) __builtin_amdgcn_exp2f(x)
#else
#define EXP2F(x) exp2f(x)
#endif
#if __has_builtin(__builtin_amdgcn_rcpf)
#define RCPF(x) __builtin_amdgcn_rcpf(x)
#else
#define RCPF(x) (1.0f / (x))
#endif

static constexpr float K2LOG2E = 2.8853900817779268f;  // 2*log2(e)

__device__ __forceinline__ short f2bf(float f) {  // RNE float->bf16 (weights, one-time)
  union { float f; unsigned u; } v; v.f = f;
  unsigned r = v.u + 0x7FFFu + ((v.u >> 16) & 1u);
  return (short)(r >> 16);
}
__device__ __forceinline__ float bf2f(short s) {
  union { unsigned u; float f; } v; v.u = ((unsigned)(unsigned short)s) << 16;
  return v.f;
}
__device__ __forceinline__ unsigned pk2bf(float a, float b) {  // v_cvt_pk_bf16_f32
  float2 t; t.x = a; t.y = b;
  union { __hip_bfloat162 h; unsigned u; } c;
  c.h = __float22bfloat162_rn(t);
  return c.u;
}

__device__ __forceinline__ s16x8 wfragA32(const float* W, int ncols, int row, int col0) {
  const float* p = W + row * ncols + col0;
  s16x8 r;
#pragma unroll
  for (int i = 0; i < 8; ++i) r[i] = f2bf(p[i]);
  return r;
}

// k-permuted Whh A-frag for the K=32 register-carried recurrence (half h=0,1):
// slot i  <-  Whh[row][ 32h + 16*(i>>2) + 4q + (i&3) ]
__device__ __forceinline__ s16x8 wfragWhh32(const float* W, int row, int q, int h) {
  const float* p = W + row * 64 + 32 * h + 4 * q;
  s16x8 r;
#pragma unroll
  for (int i = 0; i < 4; ++i) r[i] = f2bf(p[i]);
#pragma unroll
  for (int i = 0; i < 4; ++i) r[4 + i] = f2bf(p[16 + i]);
  return r;
}

// tanh(acc + bias) (bias pre-scaled by 2*log2e) -> packed bf16.
__device__ __forceinline__ s16x4 tanh_pack(fx4 acc, const float* bs) {
  float h[4];
#pragma unroll
  for (int r = 0; r < 4; ++r) {
    float e = EXP2F(__builtin_fmaf(acc[r], K2LOG2E, bs[r]));
    h[r] = __builtin_fmaf(-2.f, RCPF(e + 1.f), 1.f);
  }
  union { unsigned u[2]; s16x4 v; } p;
  p.u[0] = pk2bf(h[0], h[1]);
  p.u[1] = pk2bf(h[2], h[3]);
  return p.v;
}

union U8 { s16x8 v; s16x4 h[2]; };

__global__ __launch_bounds__(192, 2) void rnn3_hoist(
    const float* __restrict__ x,
    const float* __restrict__ Wih0, const float* __restrict__ Whh0,
    const float* __restrict__ bih0, const float* __restrict__ bhh0,
    const float* __restrict__ Wih1, const float* __restrict__ Whh1,
    const float* __restrict__ bih1, const float* __restrict__ bhh1,
    const float* __restrict__ Wih2, const float* __restrict__ Whh2,
    const float* __restrict__ bih2, const float* __restrict__ bhh2,
    const float* __restrict__ Wfc, const float* __restrict__ bfc,
    float* __restrict__ out)
{
  __shared__ __align__(16) short hb[2][8][16][72];  // [layer<2][t&7][batch][j], 36864 B

  const int tid = threadIdx.x;
  const int wv  = __builtin_amdgcn_readfirstlane(tid >> 6);  // 0..2 == layer
  const int ln  = tid & 63;
  const int q   = ln >> 4;        // K=32 k-quad / D row-quad
  const int m15 = ln & 15;
  const int bbase = (int)blockIdx.x * 16;

  // ---------- this wave's layer parameters ----------
  const float* Wih = (wv == 0) ? Wih0 : (wv == 1) ? Wih1 : Wih2;
  const float* Whh = (wv == 0) ? Whh0 : (wv == 1) ? Whh1 : Whh2;
  const float* bi  = (wv == 0) ? bih0 : (wv == 1) ? bih1 : bih2;
  const float* bh  = (wv == 0) ? bhh0 : (wv == 1) ? bhh1 : bhh2;
  const int kin = (wv == 0) ? 32 : 64;

  // ---------- weights (VGPR-resident) ----------
  s16x8 wiA[4], wiB[4];
  s16x8 wh32[4][2];
  const s16x8 z8 = {0, 0, 0, 0, 0, 0, 0, 0};
#pragma unroll
  for (int t4 = 0; t4 < 4; ++t4) {
    const int row = 16 * t4 + m15;
    wiA[t4] = wfragA32(Wih, kin, row, 8 * q);
    wiB[t4] = wv ? wfragA32(Wih, 64, row, 32 + 8 * q) : z8;   // layer 0: K=32 only
    wh32[t4][0] = wfragWhh32(Whh, row, q, 0);
    wh32[t4][1] = wfragWhh32(Whh, row, q, 1);
  }

  // ---------- biases pre-scaled; lane's j = 16*t4 + 4*q + r ----------
  float bsc[4][4];
#pragma unroll
  for (int t4 = 0; t4 < 4; ++t4)
#pragma unroll
    for (int r = 0; r < 4; ++r) {
      const int j = 16 * t4 + 4 * q + r;
      bsc[t4][r] = (bi[j] + bh[j]) * K2LOG2E;
    }

  const fx4 z4 = {0.f, 0.f, 0.f, 0.f};
  U8 hA, hB;                       // own state h_wv(t-1): hA=(j 0..31), hB=(j 32..63)
  hA.v = z8; hB.v = z8;

  // ---------- wave-0 x buffer: 4 t's of this interval (raw fx4, R12) ----------
  const float* xr = x + (size_t)(bbase + m15) * (80 * 32) + 8 * q;
  fx4 xb0[4], xb1[4];
  if (wv == 0) {
#pragma unroll
    for (int jj = 0; jj < 4; ++jj) {          // preload t = 0..3
      xb0[jj] = *(const fx4*)(xr + jj * 32);
      xb1[jj] = *(const fx4*)(xr + jj * 32 + 4);
    }
  }

  for (int m = 0; m < 22; ++m) {
    const int lt0 = 4 * (m - wv);             // first t of this interval
    if (0 <= lt0 && lt0 <= 76) {              // wave-uniform
      // ---- interval top: gather all 4 inputs ----
      s16x8 inA[4], inB[4];
      if (wv == 0) {
#pragma unroll
        for (int jj = 0; jj < 4; ++jj) {
          union { unsigned u[4]; s16x8 v; } xp;
          xp.u[0] = pk2bf(xb0[jj][0], xb0[jj][1]);
          xp.u[1] = pk2bf(xb0[jj][2], xb0[jj][3]);
          xp.u[2] = pk2bf(xb1[jj][0], xb1[jj][1]);
          xp.u[3] = pk2bf(xb1[jj][2], xb1[jj][3]);
          inA[jj] = xp.v; inB[jj] = z8;
        }
        // refill for next interval (t = lt0+4 .. lt0+7, clamped); issued now,
        // consumed at NEXT interval top -> full interval to land
#pragma unroll
        for (int jj = 0; jj < 4; ++jj) {
          const int tt = (lt0 + 4 + jj <= 79) ? lt0 + 4 + jj : 79;
          xb0[jj] = *(const fx4*)(xr + tt * 32);
          xb1[jj] = *(const fx4*)(xr + tt * 32 + 4);
        }
      } else {
#pragma unroll
        for (int jj = 0; jj < 4; ++jj) {
          const short* up = &hb[wv - 1][(lt0 + jj) & 7][m15][8 * q];
          inA[jj] = *(const s16x8*)(up);
          inB[jj] = *(const s16x8*)(up + 32);
        }
      }
      // ---- HOISTED input projection: 16 independent MFMAs for all 4 steps ----
      fx4 accp[4][4];
#pragma unroll
      for (int jj = 0; jj < 4; ++jj)
#pragma unroll
        for (int t4 = 0; t4 < 4; ++t4)
          accp[jj][t4] = MFMA32(wiA[t4], inA[jj], z4);
      if (wv) {
#pragma unroll
        for (int jj = 0; jj < 4; ++jj)
#pragma unroll
          for (int t4 = 0; t4 < 4; ++t4)
            accp[jj][t4] = MFMA32(wiB[t4], inB[jj], accp[jj][t4]);
      }
      // ---- 4 sequential steps: only 2-deep recurrence accumulate + tanh ----
#pragma unroll
      for (int jj = 0; jj < 4; ++jj) {
        const int st = (lt0 + jj) & 7;
        fx4 acc[4];
#pragma unroll
        for (int t4 = 0; t4 < 4; ++t4) acc[t4] = MFMA32(wh32[t4][0], hA.v, accp[jj][t4]);
#pragma unroll
        for (int t4 = 0; t4 < 4; ++t4) acc[t4] = MFMA32(wh32[t4][1], hB.v, acc[t4]);
        // tanh -> new own state + LDS publish for downstream (layers 0,1 only)
        U8 nA, nB;
#pragma unroll
        for (int t4 = 0; t4 < 4; ++t4) {
          s16x4 hv = tanh_pack(acc[t4], bsc[t4]);
          if (t4 < 2) nA.h[t4] = hv; else nB.h[t4 - 2] = hv;
          if (wv < 2) {
            *(s16x4*)(&hb[wv][st][m15][4 * q + 16 * t4]) = hv;
          }
        }
        hA = nA; hB = nB;
      }
    }
    __syncthreads();                          // ONE barrier per 4-step interval
  }

  // ---------- FC head: wave 2's state == h2(79), j = 16*kf + 4*q + i ----------
  if (wv == 2) {
    float sv = 0.f;
#pragma unroll
    for (int kf = 0; kf < 4; ++kf) {
      const s16x4 hh = (kf < 2) ? hA.h[kf] : hB.h[kf - 2];
#pragma unroll
      for (int i = 0; i < 4; ++i)
        sv += bf2f(hh[i]) * Wfc[16 * kf + 4 * q + i];
    }
    sv += __shfl_xor(sv, 16, 64);
    sv += __shfl_xor(sv, 32, 64);
    if (ln < 16) out[bbase + ln] = sv + bfc[0];
  }
}

extern "C" void kernel_launch(void* const* d_in, const int* in_sizes, int n_in,
                              void* d_out, int out_size, void* d_ws, size_t ws_size,
                              hipStream_t stream) {
  const float* x    = (const float*)d_in[0];
  const float* Wih0 = (const float*)d_in[1];
  const float* Whh0 = (const float*)d_in[2];
  const float* bih0 = (const float*)d_in[3];
  const float* bhh0 = (const float*)d_in[4];
  const float* Wih1 = (const float*)d_in[5];
  const float* Whh1 = (const float*)d_in[6];
  const float* bih1 = (const float*)d_in[7];
  const float* bhh1 = (const float*)d_in[8];
  const float* Wih2 = (const float*)d_in[9];
  const float* Whh2 = (const float*)d_in[10];
  const float* bih2 = (const float*)d_in[11];
  const float* bhh2 = (const float*)d_in[12];
  const float* Wfc  = (const float*)d_in[13];
  const float* bfc  = (const float*)d_in[14];

  // 512 blocks x 192 thr (3 waves = 3 pipelined layers), 16 batch rows/block:
  // 2 blocks/CU, 1.5 waves/SIMD (R12 config - best measured).
  rnn3_hoist<<<dim3(512), dim3(192), 0, stream>>>(
      x, Wih0, Whh0, bih0, bhh0, Wih1, Whh1, bih1, bhh1,
      Wih2, Whh2, bih2, bhh2, Wfc, bfc, (float*)d_out);
}